// Round 3
// baseline (326.396 us; speedup 1.0000x reference)
//
#include <hip/hip_runtime.h>

// out[16384,64] = f32(multi_hot[16384,10000]) @ embed[10000,64]
// Memory-bound on the 655 MB multi_hot stream (ideal ~100us @ 6.6 TB/s).
//
// v3: attack the A-stream memory parallelism (v2.1 == v1 == ~233us showed the
// pipeline scaffolding was never the bottleneck; the shared A access pattern is).
//   - branch-free K-loop body: tail chunk peeled out, so the compiler emits
//     counted vmcnt(N) (not vmcnt(0) drains) -> 16KB truly in flight per wave.
//   - 1KB-per-row "super-chunk" visits (256 ints): DRAM row-buffer efficiency
//     (v2.1 effectively visited 256B/row -> activate/precharge per access).
//   - 16 rows/wave (one m-tile), SPLIT=2 K-segments: 32k streams (was 65k),
//     2048 waves = 8/CU, half the atomic traffic.
//   prep kernel: embed f32 [10000][64] -> Bt bf16 [64][10240] (fragment-ready
//   [n][k], zero-padded) + zero out[] for the split-K atomics.

typedef int    int4v   __attribute__((ext_vector_type(4)));
typedef float  float4v __attribute__((ext_vector_type(4)));
typedef float  f32x4   __attribute__((ext_vector_type(4)));
typedef short  bf16x8  __attribute__((ext_vector_type(8)));
typedef unsigned int uint4v __attribute__((ext_vector_type(4)));

constexpr int M_DIM   = 16384;
constexpr int K_DIM   = 10000;
constexpr int N_DIM   = 64;
constexpr int NCH_PAD = 160;           // 64-int chunks, padded (157 real)
constexpr int KPAD    = NCH_PAD * 64;  // 10240 bf16 per Bt row
constexpr int SPLIT   = 2;
constexpr int NSC_SEG = 20;            // 256-int super-chunks per K-segment
constexpr int WMR     = 16;            // rows per wave (one 16x16 m-tile)

__device__ __forceinline__ unsigned f2bf(float x) {   // f32 -> bf16 bits, RNE
    unsigned u = __builtin_bit_cast(unsigned, x);
    u += 0x7FFFu + ((u >> 16) & 1u);
    return u >> 16;
}

// ---------------------------------------------------------------------------
// prep: blocks [0,160): transpose+convert embed -> Bt[n][k] bf16 (k>=10000 -> 0)
//       blocks [160,416): zero out[] (must precede main kernel's atomics)
// ---------------------------------------------------------------------------
__global__ __launch_bounds__(256) void prep(const float* __restrict__ em,
                                            unsigned short* __restrict__ bt,
                                            float* __restrict__ out) {
    const int tid = threadIdx.x;
    const int b   = blockIdx.x;
    if (b < NCH_PAD) {
        __shared__ float t[64][65];            // [n][k], +1 pad
        const int k0 = b * 64;
        #pragma unroll
        for (int rep = 0; rep < 16; ++rep) {   // coalesced 64x64 f32 read
            const int idx = rep * 256 + tid;
            const int k = idx >> 6, n = idx & 63;
            float v = 0.f;
            if (k0 + k < K_DIM) v = em[(k0 + k) * N_DIM + n];
            t[n][k] = v;
        }
        __syncthreads();
        const int n  = tid >> 2;               // 0..63
        const int kk = (tid & 3) * 16;         // 0..48
        unsigned w[8];
        #pragma unroll
        for (int j = 0; j < 8; ++j)
            w[j] = f2bf(t[n][kk + 2 * j]) | (f2bf(t[n][kk + 2 * j + 1]) << 16);
        uint4v lo = {w[0], w[1], w[2], w[3]};
        uint4v hi = {w[4], w[5], w[6], w[7]};
        uint4v* dst = (uint4v*)(bt + (long long)n * KPAD + k0 + kk);
        dst[0] = lo; dst[1] = hi;              // 32B contiguous per thread
    } else {
        const int b2 = b - NCH_PAD;            // 0..255
        float4v z = {0.f, 0.f, 0.f, 0.f};
        float4v* p = (float4v*)out;
        const int base = b2 * 256 + tid;
        #pragma unroll
        for (int i = 0; i < 4; ++i) p[base + i * 65536] = z;  // 4.19 MB total
    }
}

// ---------------------------------------------------------------------------
// main GEMM: 512 blocks x 256 thr = 2048 waves. w = bid*4+wv; seg = w>>10
// (uniform per block; 4 waves share the B chunk stream -> L1 reuse);
// rowblk = w&1023 -> 16 rows each.
// ---------------------------------------------------------------------------
struct AR { int4v  q0, q1, q2, q3; };          // 16 rows x 64 k-ints (1 chunk)
struct BF { bf16x8 f[4][2]; };                 // [n-tile][k-step] fragments

__global__ __launch_bounds__(256, 2) void mhe_gemm(
        const int* __restrict__ mh, const unsigned short* __restrict__ bt,
        float* __restrict__ out) {
    const int tid  = threadIdx.x;
    const int lane = tid & 63;
    const int wv   = tid >> 6;
    const int w    = (int)blockIdx.x * 4 + wv;     // 0..2047
    const int seg  = w >> 10;                      // 0..1
    const int rowblk = w & 1023;
    const int row0 = rowblk * WMR;

    const int g8 = (lane >> 4) << 3;               // k sub-offset (ints)
    const int* __restrict__ ap = mh + (long long)(row0 + (lane & 15)) * K_DIM;

    // B fragment base: lane reads Bt[nt*16 + (lane&15)][f0 + ks*32 + g8 ..+7]
    const unsigned short* __restrict__ bpn[4];
    #pragma unroll
    for (int nt = 0; nt < 4; ++nt)
        bpn[nt] = bt + (long long)(nt * 16 + (lane & 15)) * KPAD + g8;

    f32x4 acc[4] = {};   // one m-tile x 4 n-tiles

    // ints 0/1 -> packed bf16 pairs: (a | b<<16) * 0x3F80 == bf16(a) | bf16(b)<<16
    auto packA = [&](int4v qa, int4v qb) -> bf16x8 {
        uint4v x;
        x[0] = (unsigned)(qa[0] | (qa[1] << 16)) * 0x3F80u;
        x[1] = (unsigned)(qa[2] | (qa[3] << 16)) * 0x3F80u;
        x[2] = (unsigned)(qb[0] | (qb[1] << 16)) * 0x3F80u;
        x[3] = (unsigned)(qb[2] | (qb[3] << 16)) * 0x3F80u;
        return __builtin_bit_cast(bf16x8, x);
    };

    auto loadA = [&](AR& a, int f0) {               // unconditional, 4x dwordx4
        a.q0 = __builtin_nontemporal_load((const int4v*)(ap + f0 + g8));
        a.q1 = __builtin_nontemporal_load((const int4v*)(ap + f0 + g8 + 4));
        a.q2 = __builtin_nontemporal_load((const int4v*)(ap + f0 + 32 + g8));
        a.q3 = __builtin_nontemporal_load((const int4v*)(ap + f0 + 32 + g8 + 4));
    };

    auto loadB = [&](BF& b, int f0) {               // L2-resident, zero-padded
        #pragma unroll
        for (int nt = 0; nt < 4; ++nt) {
            b.f[nt][0] = *(const bf16x8*)(bpn[nt] + f0);
            b.f[nt][1] = *(const bf16x8*)(bpn[nt] + f0 + 32);
        }
    };

    auto computeChunk = [&](const AR& a, const BF& b) {
        bf16x8 a0 = packA(a.q0, a.q1);              // k 0..31 of chunk
        bf16x8 a1 = packA(a.q2, a.q3);              // k 32..63
        #pragma unroll
        for (int nt = 0; nt < 4; ++nt) {
            acc[nt] = __builtin_amdgcn_mfma_f32_16x16x32_bf16(a0, b.f[nt][0], acc[nt], 0, 0, 0);
            acc[nt] = __builtin_amdgcn_mfma_f32_16x16x32_bf16(a1, b.f[nt][1], acc[nt], 0, 0, 0);
        }
    };

    // Branch-free super-chunk loop: 256 ints (1KB/row) per iteration.
    // Issue order (B then A) + in-order vmcnt => descending counted waits,
    // 16KB of A in flight per wave at the wait point.
    const int sc0   = seg * NSC_SEG;
    const int nfull = NSC_SEG - seg;   // seg0: 20 full; seg1: 19 full + tail
    for (int s = 0; s < nfull; ++s) {
        const int F = (sc0 + s) * 256;
        BF b01[2];
        loadB(b01[0], F);
        loadB(b01[1], F + 64);
        AR a[4];
        #pragma unroll
        for (int cc = 0; cc < 4; ++cc) loadA(a[cc], F + cc * 64);
        computeChunk(a[0], b01[0]);
        computeChunk(a[1], b01[1]);
        BF b23[2];
        loadB(b23[0], F + 128);
        loadB(b23[1], F + 192);
        computeChunk(a[2], b23[0]);
        computeChunk(a[3], b23[1]);
    }

    if (seg == 1) {                     // K tail: chunk 156, ints 9984..9999
        const int f0 = 9984;
        AR a; a.q0 = {}; a.q1 = {}; a.q2 = {}; a.q3 = {};
        if (f0 + g8 + 4 <= K_DIM) a.q0 = *(const int4v*)(ap + f0 + g8);
        if (f0 + g8 + 8 <= K_DIM) a.q1 = *(const int4v*)(ap + f0 + g8 + 4);
        // q2,q3 (k >= 10016) stay zero
        BF b;
        loadB(b, f0);                   // Bt zero-padded past 10000
        computeChunk(a, b);
    }

    // C/D layout: col = lane&15, row = (lane>>4)*4 + i   [m89-verified]
    const int crow = row0 + ((lane >> 4) << 2);
    const int ccol = lane & 15;
    #pragma unroll
    for (int nt = 0; nt < 4; ++nt)
        #pragma unroll
        for (int i = 0; i < 4; ++i)
            unsafeAtomicAdd(&out[(long long)(crow + i) * N_DIM + nt * 16 + ccol],
                            acc[nt][i]);
}

extern "C" void kernel_launch(void* const* d_in, const int* in_sizes, int n_in,
                              void* d_out, int out_size, void* d_ws, size_t ws_size,
                              hipStream_t stream) {
    const int*   mh  = (const int*)d_in[0];
    const float* em  = (const float*)d_in[1];
    float*       out = (float*)d_out;
    unsigned short* bt = (unsigned short*)d_ws;    // needs 64*10240*2 = 1.31 MB
    (void)in_sizes; (void)n_in; (void)out_size; (void)ws_size;

    prep<<<dim3(NCH_PAD + 256), dim3(256), 0, stream>>>(em, bt, out);
    mhe_gemm<<<dim3((M_DIM / WMR) * SPLIT / 4), dim3(256), 0, stream>>>(mh, bt, out);
}

// Round 4
// 289.244 us; speedup vs baseline: 1.1284x; 1.1284x over previous
//
#include <hip/hip_runtime.h>

// out[16384,64] = f32(multi_hot[16384,10000]) @ embed[10000,64]
//
// v4: two-pass bit-pack. Evidence: v1 (LDS+barriers) == v2.1 (reg-DB) == 233us,
// v3 (deeper batching) == 326us -> the scattered A-fragment read pattern
// (16B/lane across 16 rows, 40KB stride, 256B/row-visit) caps the memory
// system at ~2.8 TB/s, while contiguous streams hit 6.6 TB/s (fill kernels).
// multi_hot is 0/1: 655MB carrying 20.5MB of information. So:
//   pass 1 (pack):  contiguous 1KB/instr reads of multi_hot, 4x __ballot per
//                   int4 -> packed bits [16384][160]u64 (21MB). Ballot order
//                   (bit l of word j <-> int 4l+j) is ABSORBED into Bt's slot
//                   permutation -- GEMM sums over k, any shared k-order works.
//                   Also: permuted Bt bf16 [64][10240] prep + out zeroing.
//   pass 2 (gemm):  reads 21MB packed A, expands bits->bf16 in VALU, same
//                   verified MFMA fragment + split-K atomic structure.
//                   Padded slots have zero A-bits -> fully branch-free.

typedef int    int4v   __attribute__((ext_vector_type(4)));
typedef float  float4v __attribute__((ext_vector_type(4)));
typedef float  f32x4   __attribute__((ext_vector_type(4)));
typedef short  bf16x8  __attribute__((ext_vector_type(8)));
typedef unsigned int uint4v __attribute__((ext_vector_type(4)));

constexpr int M_DIM  = 16384;
constexpr int K_DIM  = 10000;
constexpr int N_DIM  = 64;
constexpr int WORDS  = 160;            // u64 words per packed row (10240 bits)
constexpr int SLOTS  = 10240;          // packed k-slots (zero-padded)
constexpr int SPLIT  = 4;
constexpr int CH_SEG = WORDS / SPLIT;  // 40 chunks (u64 words) per K-segment

__device__ __forceinline__ unsigned f2bf(float x) {   // f32 -> bf16 bits, RNE
    unsigned u = __builtin_bit_cast(unsigned, x);
    u += 0x7FFFu + ((u >> 16) & 1u);
    return u >> 16;
}

// packed slot s -> original k index (ballot layout: bit l of word j = int 4l+j)
__device__ __forceinline__ int orig_of(int s) {
    const int grp = s >> 8, rem = s & 255, j = rem >> 6, l = rem & 63;
    return (grp << 8) + 4 * l + j;
}

// ---------------------------------------------------------------------------
// pack: blocks [0,4096): bit-pack 4 rows/block (1 row/wave), contiguous reads.
//       blocks [4096,4256): permuted Bt prep.  blocks [4256,4512): zero out[].
// ---------------------------------------------------------------------------
__global__ __launch_bounds__(256) void pack(const int* __restrict__ mh,
                                            const float* __restrict__ em,
                                            unsigned long long* __restrict__ pa,
                                            unsigned short* __restrict__ bt,
                                            float* __restrict__ out) {
    const int b = blockIdx.x, tid = threadIdx.x;
    if (b < 4096) {
        const int lane = tid & 63, wv = tid >> 6;
        const int row  = b * 4 + wv;
        const int4v* rp = (const int4v*)(mh + (long long)row * K_DIM);
        unsigned long long* wp = pa + (long long)row * WORDS;

        auto emit = [&](int g, int4v v) {   // 256 ints -> 4 u64 words
            unsigned long long w0 = __ballot(v[0] != 0);
            unsigned long long w1 = __ballot(v[1] != 0);
            unsigned long long w2 = __ballot(v[2] != 0);
            unsigned long long w3 = __ballot(v[3] != 0);
            if (lane < 4) {
                unsigned long long w = lane == 0 ? w0 : lane == 1 ? w1
                                     : lane == 2 ? w2 : w3;
                wp[g * 4 + lane] = w;
            }
        };

        // 39 full groups (ints 0..9983), software prefetch one ahead
        int4v vc = __builtin_nontemporal_load(rp + lane);       // lane-contig 1KB
        for (int g = 0; g < 38; ++g) {
            int4v vn = __builtin_nontemporal_load(rp + (g + 1) * 64 + lane);
            emit(g, vc);
            vc = vn;
        }
        int4v vt = {};                       // tail group 39: ints 9984..9999
        if (lane < 4) vt = rp[39 * 64 + lane];
        emit(38, vc);
        emit(39, vt);                        // bits past K_DIM = 0
    } else if (b < 4096 + 160) {
        // Bt[n][s] = bf16(em[orig_of(s)][n]) for the ballot-permuted slot order
        const int s0 = (b - 4096) * 64;
        const int n = tid >> 2, q = tid & 3;
        unsigned u[8];
        #pragma unroll
        for (int i = 0; i < 8; ++i) {
            const int sA = s0 + q * 16 + 2 * i, sB = sA + 1;
            const int oA = orig_of(sA), oB = orig_of(sB);
            const unsigned lo = (oA < K_DIM) ? f2bf(em[oA * N_DIM + n]) : 0u;
            const unsigned hi = (oB < K_DIM) ? f2bf(em[oB * N_DIM + n]) : 0u;
            u[i] = lo | (hi << 16);
        }
        uint4v* dst = (uint4v*)(bt + (long long)n * SLOTS + s0 + q * 16);
        uint4v w0 = {u[0], u[1], u[2], u[3]};
        uint4v w1 = {u[4], u[5], u[6], u[7]};
        dst[0] = w0; dst[1] = w1;
    } else {
        const int b3 = b - 4256;             // zero out[] (4MB) for atomics
        float4v z = {0.f, 0.f, 0.f, 0.f};
        float4v* p = (float4v*)out;
        const int base = b3 * 256 + tid;
        #pragma unroll
        for (int i = 0; i < 4; ++i) p[base + i * 65536] = z;
    }
}

// ---------------------------------------------------------------------------
// gemm: 1024 blocks x 256 thr = 4096 waves. w = bid*4+wv; seg = w>>10 (block-
// uniform), rowwave = w&1023 -> 16 rows. Chunk = one u64 word = 64 k-slots =
// 2 MFMA k-steps. A-bits expand to bf16 in VALU; B from L2-resident Bt.
// ---------------------------------------------------------------------------
struct BF { bf16x8 f[4][2]; };               // [n-tile][k-step] fragments

__global__ __launch_bounds__(256, 3) void mhe_gemm(
        const unsigned long long* __restrict__ pa,
        const unsigned short* __restrict__ bt,
        float* __restrict__ out) {
    const int tid  = threadIdx.x;
    const int lane = tid & 63;
    const int wv   = tid >> 6;
    const int w    = (int)blockIdx.x * 4 + wv;     // 0..4095
    const int seg  = w >> 10;                      // 0..3
    const int rw   = w & 1023;
    const int row0 = rw * 16;
    const int g    = lane >> 4;                    // byte-slot within k-step

    const unsigned long long* __restrict__ ap =
        pa + (long long)(row0 + (lane & 15)) * WORDS;

    const unsigned short* __restrict__ bpn[4];
    #pragma unroll
    for (int nt = 0; nt < 4; ++nt)
        bpn[nt] = bt + (long long)(nt * 16 + (lane & 15)) * SLOTS + g * 8;

    f32x4 acc[4] = {};

    auto expand = [&](unsigned byte) -> bf16x8 {   // 8 bits -> 8 bf16 (4 words)
        uint4v x;
        #pragma unroll
        for (int i = 0; i < 4; ++i) {
            const unsigned t = byte >> (2 * i);
            x[i] = ((t & 1u) | ((t & 2u) << 15)) * 0x3F80u;
        }
        return __builtin_bit_cast(bf16x8, x);
    };

    auto loadB = [&](BF& bb, int c) {
        const int f0 = c * 64;
        #pragma unroll
        for (int nt = 0; nt < 4; ++nt) {
            bb.f[nt][0] = *(const bf16x8*)(bpn[nt] + f0);
            bb.f[nt][1] = *(const bf16x8*)(bpn[nt] + f0 + 32);
        }
    };

    auto computeChunk = [&](unsigned long long pw, const BF& bb) {
        const unsigned lo = (unsigned)pw, hi = (unsigned)(pw >> 32);
        bf16x8 a0 = expand((lo >> (8 * g)) & 255u);   // k-step 0
        bf16x8 a1 = expand((hi >> (8 * g)) & 255u);   // k-step 1
        #pragma unroll
        for (int nt = 0; nt < 4; ++nt) {
            acc[nt] = __builtin_amdgcn_mfma_f32_16x16x32_bf16(a0, bb.f[nt][0], acc[nt], 0, 0, 0);
            acc[nt] = __builtin_amdgcn_mfma_f32_16x16x32_bf16(a1, bb.f[nt][1], acc[nt], 0, 0, 0);
        }
    };

    // branch-free K loop with one-chunk register prefetch (no barriers).
    // Words 156..159 carry zero bits (pack padding) -> contribute nothing.
    const int c0 = seg * CH_SEG;
    unsigned long long pwA = ap[c0];
    BF bA; loadB(bA, c0);
    for (int c = c0; c < c0 + CH_SEG - 1; ++c) {
        unsigned long long pwB = ap[c + 1];
        BF bB; loadB(bB, c + 1);
        computeChunk(pwA, bA);
        pwA = pwB; bA = bB;
    }
    computeChunk(pwA, bA);

    // C/D layout: col = lane&15, row = (lane>>4)*4 + i   [m89-verified]
    const int crow = row0 + (g << 2);
    const int ccol = lane & 15;
    #pragma unroll
    for (int nt = 0; nt < 4; ++nt)
        #pragma unroll
        for (int i = 0; i < 4; ++i)
            unsafeAtomicAdd(&out[(long long)(crow + i) * N_DIM + nt * 16 + ccol],
                            acc[nt][i]);
}

extern "C" void kernel_launch(void* const* d_in, const int* in_sizes, int n_in,
                              void* d_out, int out_size, void* d_ws, size_t ws_size,
                              hipStream_t stream) {
    const int*   mh  = (const int*)d_in[0];
    const float* em  = (const float*)d_in[1];
    float*       out = (float*)d_out;
    unsigned long long* pa = (unsigned long long*)d_ws;              // 21.0 MB
    unsigned short*     bt = (unsigned short*)((char*)d_ws +
                             (size_t)M_DIM * WORDS * 8);             // +1.3 MB
    (void)in_sizes; (void)n_in; (void)out_size; (void)ws_size;

    pack<<<dim3(4512), dim3(256), 0, stream>>>(mh, em, pa, bt, out);
    mhe_gemm<<<dim3(1024), dim3(256), 0, stream>>>(pa, bt, out);
}

// Round 5
// 288.016 us; speedup vs baseline: 1.1333x; 1.0043x over previous
//
#include <hip/hip_runtime.h>

// out[16384,64] = f32(multi_hot[16384,10000]) @ embed[10000,64]
//
// v5: copy-shaped pack front. Evidence chain: v1(scatter+LDS)=233us,
// v2.1(scatter+regDB)=236us, v3(scatter, deeper batch)=326us,
// v4(per-wave-contiguous rows)=289us (pack ~230us @2.8TB/s). All read
// patterns where resident waves own PRIVATE streams run at ~2.8 TB/s;
// the chip's 6.3-6.5 TB/s patterns (fill, float4 copy) advance ONE compact
// sequential front: consecutive waves <-> consecutive addresses, same instant.
//   pass 1 (pack): grid-stride over 1KB "groups" (256 ints of one row);
//                  wave w handles group j = w + t*8192 -> the 8192 resident
//                  waves cover a contiguous 8MB window per iteration. 4x
//                  __ballot per int4 -> packed bits [16384][160]u64 (21MB).
//                  Ballot slot order is absorbed into Bt's slot permutation.
//                  Plus: permuted Bt bf16 [64][10240] prep + out zeroing.
//   pass 2 (gemm): byte-identical to v4 (verified): reads 21MB packed A,
//                  expands bits->bf16 in VALU, MFMA, split-K atomics.

typedef int    int4v   __attribute__((ext_vector_type(4)));
typedef float  float4v __attribute__((ext_vector_type(4)));
typedef float  f32x4   __attribute__((ext_vector_type(4)));
typedef short  bf16x8  __attribute__((ext_vector_type(8)));
typedef unsigned int uint4v __attribute__((ext_vector_type(4)));

constexpr int M_DIM  = 16384;
constexpr int K_DIM  = 10000;
constexpr int N_DIM  = 64;
constexpr int WORDS  = 160;            // u64 words per packed row (10240 bits)
constexpr int SLOTS  = 10240;          // packed k-slots (zero-padded)
constexpr int SPLIT  = 4;
constexpr int CH_SEG = WORDS / SPLIT;  // 40 chunks (u64 words) per K-segment

constexpr int GPR         = 40;                    // 1KB groups per row
constexpr int GROUPS_TOT  = M_DIM * GPR;           // 655,360
constexpr int PACK_BLOCKS = 2048;                  // all-resident at 8 wv/SIMD
constexpr int PACK_WAVES  = PACK_BLOCKS * 4;       // 8192
constexpr int PACK_ITERS  = GROUPS_TOT / PACK_WAVES;  // 80

__device__ __forceinline__ unsigned f2bf(float x) {   // f32 -> bf16 bits, RNE
    unsigned u = __builtin_bit_cast(unsigned, x);
    u += 0x7FFFu + ((u >> 16) & 1u);
    return u >> 16;
}

// packed slot s -> original k index (ballot layout: bit l of word j = int 4l+j)
__device__ __forceinline__ int orig_of(int s) {
    const int grp = s >> 8, rem = s & 255, j = rem >> 6, l = rem & 63;
    return (grp << 8) + 4 * l + j;
}

// ---------------------------------------------------------------------------
// pack: blocks [0,2048): copy-front bit-pack (grid-stride over groups).
//       blocks [2048,2208): permuted Bt prep.  blocks [2208,2464): zero out[].
// ---------------------------------------------------------------------------
__global__ __launch_bounds__(256) void pack(const int* __restrict__ mh,
                                            const float* __restrict__ em,
                                            unsigned long long* __restrict__ pa,
                                            unsigned short* __restrict__ bt,
                                            float* __restrict__ out) {
    const int b = blockIdx.x, tid = threadIdx.x;
    if (b < PACK_BLOCKS) {
        const int lane = tid & 63, wv = tid >> 6;
        const int w = b * 4 + wv;                  // global wave id, 0..8191

        auto loadg = [&](int j) -> int4v {         // group j: row j/40, grp j%40
            const int row = j / GPR, g = j - row * GPR;
            int4v v = {};
            if (g < GPR - 1 || lane < 4)           // tail group: ints 9984..9999
                v = *(const int4v*)(mh + (long long)row * K_DIM + g * 256 + lane * 4);
            return v;
        };
        auto emit = [&](int j, int4v v) {          // 256 ints -> 4 u64 words
            const int row = j / GPR, g = j - row * GPR;
            unsigned long long w0 = __ballot(v[0] != 0);
            unsigned long long w1 = __ballot(v[1] != 0);
            unsigned long long w2 = __ballot(v[2] != 0);
            unsigned long long w3 = __ballot(v[3] != 0);
            if (lane < 4) {
                unsigned long long ww = lane == 0 ? w0 : lane == 1 ? w1
                                      : lane == 2 ? w2 : w3;
                pa[(long long)row * WORDS + g * 4 + lane] = ww;
            }
        };

        int j = w;
        int4v vc = loadg(j);                       // depth-2 software pipeline
        for (int t = 0; t < PACK_ITERS - 1; ++t) {
            int4v vn = loadg(j + PACK_WAVES);
            emit(j, vc);
            vc = vn; j += PACK_WAVES;
        }
        emit(j, vc);
    } else if (b < PACK_BLOCKS + 160) {
        // Bt[n][s] = bf16(em[orig_of(s)][n]) for the ballot-permuted slot order
        const int s0 = (b - PACK_BLOCKS) * 64;
        const int n = tid >> 2, q = tid & 3;
        unsigned u[8];
        #pragma unroll
        for (int i = 0; i < 8; ++i) {
            const int sA = s0 + q * 16 + 2 * i, sB = sA + 1;
            const int oA = orig_of(sA), oB = orig_of(sB);
            const unsigned lo = (oA < K_DIM) ? f2bf(em[oA * N_DIM + n]) : 0u;
            const unsigned hi = (oB < K_DIM) ? f2bf(em[oB * N_DIM + n]) : 0u;
            u[i] = lo | (hi << 16);
        }
        uint4v* dst = (uint4v*)(bt + (long long)n * SLOTS + s0 + q * 16);
        uint4v w0 = {u[0], u[1], u[2], u[3]};
        uint4v w1 = {u[4], u[5], u[6], u[7]};
        dst[0] = w0; dst[1] = w1;
    } else {
        const int b3 = b - (PACK_BLOCKS + 160);    // zero out[] (4MB) for atomics
        float4v z = {0.f, 0.f, 0.f, 0.f};
        float4v* p = (float4v*)out;
        const int base = b3 * 256 + tid;
        #pragma unroll
        for (int i = 0; i < 4; ++i) p[base + i * 65536] = z;
    }
}

// ---------------------------------------------------------------------------
// gemm: 1024 blocks x 256 thr = 4096 waves. w = bid*4+wv; seg = w>>10 (block-
// uniform), rowwave = w&1023 -> 16 rows. Chunk = one u64 word = 64 k-slots =
// 2 MFMA k-steps. A-bits expand to bf16 in VALU; B from L2-resident Bt.
// (byte-identical to v4 -- verified correct)
// ---------------------------------------------------------------------------
struct BF { bf16x8 f[4][2]; };               // [n-tile][k-step] fragments

__global__ __launch_bounds__(256, 3) void mhe_gemm(
        const unsigned long long* __restrict__ pa,
        const unsigned short* __restrict__ bt,
        float* __restrict__ out) {
    const int tid  = threadIdx.x;
    const int lane = tid & 63;
    const int wv   = tid >> 6;
    const int w    = (int)blockIdx.x * 4 + wv;     // 0..4095
    const int seg  = w >> 10;                      // 0..3
    const int rw   = w & 1023;
    const int row0 = rw * 16;
    const int g    = lane >> 4;                    // byte-slot within k-step

    const unsigned long long* __restrict__ ap =
        pa + (long long)(row0 + (lane & 15)) * WORDS;

    const unsigned short* __restrict__ bpn[4];
    #pragma unroll
    for (int nt = 0; nt < 4; ++nt)
        bpn[nt] = bt + (long long)(nt * 16 + (lane & 15)) * SLOTS + g * 8;

    f32x4 acc[4] = {};

    auto expand = [&](unsigned byte) -> bf16x8 {   // 8 bits -> 8 bf16 (4 words)
        uint4v x;
        #pragma unroll
        for (int i = 0; i < 4; ++i) {
            const unsigned t = byte >> (2 * i);
            x[i] = ((t & 1u) | ((t & 2u) << 15)) * 0x3F80u;
        }
        return __builtin_bit_cast(bf16x8, x);
    };

    auto loadB = [&](BF& bb, int c) {
        const int f0 = c * 64;
        #pragma unroll
        for (int nt = 0; nt < 4; ++nt) {
            bb.f[nt][0] = *(const bf16x8*)(bpn[nt] + f0);
            bb.f[nt][1] = *(const bf16x8*)(bpn[nt] + f0 + 32);
        }
    };

    auto computeChunk = [&](unsigned long long pw, const BF& bb) {
        const unsigned lo = (unsigned)pw, hi = (unsigned)(pw >> 32);
        bf16x8 a0 = expand((lo >> (8 * g)) & 255u);   // k-step 0
        bf16x8 a1 = expand((hi >> (8 * g)) & 255u);   // k-step 1
        #pragma unroll
        for (int nt = 0; nt < 4; ++nt) {
            acc[nt] = __builtin_amdgcn_mfma_f32_16x16x32_bf16(a0, bb.f[nt][0], acc[nt], 0, 0, 0);
            acc[nt] = __builtin_amdgcn_mfma_f32_16x16x32_bf16(a1, bb.f[nt][1], acc[nt], 0, 0, 0);
        }
    };

    // branch-free K loop with one-chunk register prefetch (no barriers).
    // Words 156..159: bits past K_DIM are zero (masked in pack) -> no effect.
    const int c0 = seg * CH_SEG;
    unsigned long long pwA = ap[c0];
    BF bA; loadB(bA, c0);
    for (int c = c0; c < c0 + CH_SEG - 1; ++c) {
        unsigned long long pwB = ap[c + 1];
        BF bB; loadB(bB, c + 1);
        computeChunk(pwA, bA);
        pwA = pwB; bA = bB;
    }
    computeChunk(pwA, bA);

    // C/D layout: col = lane&15, row = (lane>>4)*4 + i   [m89-verified]
    const int crow = row0 + (g << 2);
    const int ccol = lane & 15;
    #pragma unroll
    for (int nt = 0; nt < 4; ++nt)
        #pragma unroll
        for (int i = 0; i < 4; ++i)
            unsafeAtomicAdd(&out[(long long)(crow + i) * N_DIM + nt * 16 + ccol],
                            acc[nt][i]);
}

extern "C" void kernel_launch(void* const* d_in, const int* in_sizes, int n_in,
                              void* d_out, int out_size, void* d_ws, size_t ws_size,
                              hipStream_t stream) {
    const int*   mh  = (const int*)d_in[0];
    const float* em  = (const float*)d_in[1];
    float*       out = (float*)d_out;
    unsigned long long* pa = (unsigned long long*)d_ws;              // 21.0 MB
    unsigned short*     bt = (unsigned short*)((char*)d_ws +
                             (size_t)M_DIM * WORDS * 8);             // +1.3 MB
    (void)in_sizes; (void)n_in; (void)out_size; (void)ws_size;

    pack<<<dim3(PACK_BLOCKS + 160 + 256), dim3(256), 0, stream>>>(mh, em, pa, bt, out);
    mhe_gemm<<<dim3(1024), dim3(256), 0, stream>>>(pa, bt, out);
}

// Round 6
// 275.504 us; speedup vs baseline: 1.1847x; 1.0454x over previous
//
#include <hip/hip_runtime.h>

// out[16384,64] = f32(multi_hot[16384,10000]) @ embed[10000,64]
//
// v6: FUSED pack+gemm. Evidence: v1/v2.1 (scattered reads) = 233-236us,
// v4/v5 (two-pass, sequential/copy-front contiguous reads) = 288-289us with
// pack ~230us -> streaming READ bandwidth is ~2.85 TB/s on this box REGARDLESS
// of access pattern ("6.3 TB/s achievable" is FETCH+WRITE sum; m13 copy =
// 3.15/dir; the 6.5 TB/s fills are write-only). So: eliminate v4/v5's 21MB
// round-trip + second launch, keep the contiguous read shape, overlap compute
// under the read stream via multi-block residency.
//   btprep: embed f32 -> ballot-permuted Bt bf16 [64][10240] (verified v4/v5).
//   fused:  1024 blocks x 256 thr, 4 blocks/CU. Block owns 16 contiguous rows
//           (640KB contiguous). Phase 1: cooperative read + __ballot bit-pack
//           into LDS [16][161]u64 (20.6KB, padded stride -> conflict-free b64).
//           One barrier. Phase 2: per-wave n-tile gemm, A from LDS (broadcast),
//           B from L2-resident Bt, full K per block -> direct stores, no
//           atomics, no zero-init. Phases of co-resident blocks overlap.

typedef int    int4v   __attribute__((ext_vector_type(4)));
typedef float  f32x4   __attribute__((ext_vector_type(4)));
typedef short  bf16x8  __attribute__((ext_vector_type(8)));
typedef unsigned int uint4v __attribute__((ext_vector_type(4)));

constexpr int M_DIM = 16384;
constexpr int K_DIM = 10000;
constexpr int N_DIM = 64;
constexpr int WORDS = 160;             // u64 words per packed row (10240 bits)
constexpr int WPAD  = 161;             // LDS row stride in u64 (bank spread)
constexpr int SLOTS = 10240;           // packed k-slots (zero-padded)
constexpr int GPR   = 40;              // 256-int groups per row

__device__ __forceinline__ unsigned f2bf(float x) {   // f32 -> bf16 bits, RNE
    unsigned u = __builtin_bit_cast(unsigned, x);
    u += 0x7FFFu + ((u >> 16) & 1u);
    return u >> 16;
}

// packed slot s -> original k (ballot layout: bit l of word g*4+j = int g*256+4l+j)
__device__ __forceinline__ int orig_of(int s) {
    const int grp = s >> 8, rem = s & 255, j = rem >> 6, l = rem & 63;
    return (grp << 8) + 4 * l + j;
}

// ---------------------------------------------------------------------------
// btprep: Bt[n][s] = bf16(em[orig_of(s)][n])  (byte-identical logic to v4/v5)
// ---------------------------------------------------------------------------
__global__ __launch_bounds__(256) void btprep(const float* __restrict__ em,
                                              unsigned short* __restrict__ bt) {
    const int tid = threadIdx.x;
    const int s0  = blockIdx.x * 64;
    const int n = tid >> 2, q = tid & 3;
    unsigned u[8];
    #pragma unroll
    for (int i = 0; i < 8; ++i) {
        const int sA = s0 + q * 16 + 2 * i, sB = sA + 1;
        const int oA = orig_of(sA), oB = orig_of(sB);
        const unsigned lo = (oA < K_DIM) ? f2bf(em[oA * N_DIM + n]) : 0u;
        const unsigned hi = (oB < K_DIM) ? f2bf(em[oB * N_DIM + n]) : 0u;
        u[i] = lo | (hi << 16);
    }
    uint4v* dst = (uint4v*)(bt + (long long)n * SLOTS + s0 + q * 16);
    uint4v w0 = {u[0], u[1], u[2], u[3]};
    uint4v w1 = {u[4], u[5], u[6], u[7]};
    dst[0] = w0; dst[1] = w1;
}

// ---------------------------------------------------------------------------
// fused: phase 1 read+pack (contiguous), phase 2 gemm from LDS + L2 Bt.
// ---------------------------------------------------------------------------
__global__ __launch_bounds__(256, 4) void fused(const int* __restrict__ mh,
                                                const unsigned short* __restrict__ bt,
                                                float* __restrict__ out) {
    __shared__ unsigned long long pk[16][WPAD];    // packed bits, 20.6 KB

    const int tid  = threadIdx.x;
    const int lane = tid & 63;
    const int wv   = tid >> 6;
    const long long r0 = (long long)blockIdx.x * 16;

    // ---- phase 1: block streams its 16 rows (640KB contiguous), bit-packs.
    // wave wv takes groups g = wv, wv+4, ... of each row -> at any instant the
    // 4 waves read 4KB contiguous; block walks rows linearly.
    for (int r = 0; r < 16; ++r) {
        const int* __restrict__ rp = mh + (r0 + r) * (long long)K_DIM;
        #pragma unroll
        for (int gg = 0; gg < 10; ++gg) {
            const int g = wv + gg * 4;             // 0..39
            int4v v = {};
            if (g < GPR - 1 || lane < 4)           // g=39: ints 9984..9999 only
                v = *(const int4v*)(rp + g * 256 + lane * 4);
            // all lanes reconverge; ballot over the full wave (inactive -> 0)
            unsigned long long b0 = __ballot(v[0] != 0);
            unsigned long long b1 = __ballot(v[1] != 0);
            unsigned long long b2 = __ballot(v[2] != 0);
            unsigned long long b3 = __ballot(v[3] != 0);
            if (lane < 4) {
                unsigned long long w = lane == 0 ? b0 : lane == 1 ? b1
                                     : lane == 2 ? b2 : b3;
                pk[r][g * 4 + lane] = w;
            }
        }
    }
    __syncthreads();

    // ---- phase 2: wave wv computes n-tile wv (cols wv*16..+15) x 16 rows,
    // full K. A: ds_read_b64 pk[lane&15][c] (4-way broadcast, conflict-free
    // via WPAD=161). B: Bt rows wv*16+(lane&15), L2-resident.
    const int g = lane >> 4;                       // byte-slot within k-step
    const unsigned short* __restrict__ bp =
        bt + (long long)(wv * 16 + (lane & 15)) * SLOTS + g * 8;
    const int ar = lane & 15;

    f32x4 acc = {0.f, 0.f, 0.f, 0.f};

    auto expand = [&](unsigned byte) -> bf16x8 {   // 8 bits -> 8 bf16
        uint4v x;
        #pragma unroll
        for (int i = 0; i < 4; ++i) {
            const unsigned t = byte >> (2 * i);
            x[i] = ((t & 1u) | ((t & 2u) << 15)) * 0x3F80u;
        }
        return __builtin_bit_cast(bf16x8, x);
    };

    unsigned long long awC = pk[ar][0];
    bf16x8 b0C = *(const bf16x8*)(bp);
    bf16x8 b1C = *(const bf16x8*)(bp + 32);
    for (int c = 0; c < WORDS - 1; ++c) {
        unsigned long long awN = pk[ar][c + 1];    // prefetch next chunk
        bf16x8 b0N = *(const bf16x8*)(bp + (c + 1) * 64);
        bf16x8 b1N = *(const bf16x8*)(bp + (c + 1) * 64 + 32);
        const unsigned lo = (unsigned)awC, hi = (unsigned)(awC >> 32);
        bf16x8 a0 = expand((lo >> (8 * g)) & 255u);
        bf16x8 a1 = expand((hi >> (8 * g)) & 255u);
        acc = __builtin_amdgcn_mfma_f32_16x16x32_bf16(a0, b0C, acc, 0, 0, 0);
        acc = __builtin_amdgcn_mfma_f32_16x16x32_bf16(a1, b1C, acc, 0, 0, 0);
        awC = awN; b0C = b0N; b1C = b1N;
    }
    {
        const unsigned lo = (unsigned)awC, hi = (unsigned)(awC >> 32);
        bf16x8 a0 = expand((lo >> (8 * g)) & 255u);
        bf16x8 a1 = expand((hi >> (8 * g)) & 255u);
        acc = __builtin_amdgcn_mfma_f32_16x16x32_bf16(a0, b0C, acc, 0, 0, 0);
        acc = __builtin_amdgcn_mfma_f32_16x16x32_bf16(a1, b1C, acc, 0, 0, 0);
    }

    // C/D layout: col = lane&15, row = (lane>>4)*4 + i   [m89-verified]
    const long long orow = r0 + g * 4;
    const int ocol = wv * 16 + (lane & 15);
    #pragma unroll
    for (int i = 0; i < 4; ++i)
        out[(orow + i) * N_DIM + ocol] = acc[i];
}

extern "C" void kernel_launch(void* const* d_in, const int* in_sizes, int n_in,
                              void* d_out, int out_size, void* d_ws, size_t ws_size,
                              hipStream_t stream) {
    const int*   mh  = (const int*)d_in[0];
    const float* em  = (const float*)d_in[1];
    float*       out = (float*)d_out;
    unsigned short* bt = (unsigned short*)d_ws;    // 64*10240*2 = 1.31 MB
    (void)in_sizes; (void)n_in; (void)out_size; (void)ws_size;

    btprep<<<dim3(SLOTS / 64), dim3(256), 0, stream>>>(em, bt);
    fused<<<dim3(M_DIM / 16), dim3(256), 0, stream>>>(mh, bt, out);
}

// Round 7
// 232.090 us; speedup vs baseline: 1.4063x; 1.1871x over previous
//
#include <hip/hip_runtime.h>

// out[16384,64] = f32(multi_hot[16384,10000]) @ embed[10000,64]
// Memory-bound on the 655 MB multi_hot stream. bf16 MFMA GEMM:
//   BM=32, BK=64, grid=512 blocks x 256 thr (4 waves: 2 M-strips x 2 N-halves).
//   A: direct global->reg fragment loads (int 0/1 -> bf16 via one mul per pair).
//   B: staged to LDS [n][k] bf16 (KSTRIDE=144 pad -> conflict-free ds_read_b128),
//      double-buffered, 1 barrier/chunk, loads issued one chunk ahead.
//
// SESSION VERDICT (R0-R6): this kernel runs at 232.7us = 2.82 TB/s effective
// read rate on the mandatory 655 MB stream. Six structural redesigns
// (barrier-free reg-DB 236us; deep batch 326us; two-pass bit-pack 288-289us
// with a pure contiguous pack phase at ~230us; copy-shaped front 288us; fused
// pack+gemm 275us) all bottom out at the same ~2.82-2.85 TB/s streaming-READ
// rate regardless of access pattern -- the box's per-direction read ceiling
// (corpus "6.3 TB/s" figures are read+write sums; fills are write-only).
// 655.36 MB / 2.85 TB/s = ~230us floor; this kernel is within 1.2% of it.

typedef int    int4v   __attribute__((ext_vector_type(4)));
typedef float  float4v __attribute__((ext_vector_type(4)));
typedef float  f32x4   __attribute__((ext_vector_type(4)));
typedef short  bf16x8  __attribute__((ext_vector_type(8)));
typedef unsigned int uint4v __attribute__((ext_vector_type(4)));
typedef unsigned int uint2v __attribute__((ext_vector_type(2)));

constexpr int M_DIM   = 16384;
constexpr int K_DIM   = 10000;
constexpr int N_DIM   = 64;
constexpr int BM      = 32;
constexpr int BK      = 64;
constexpr int NCH_PAD = 158;   // ceil(10000/64)=157 chunks, pad to even (chunk 157 = zeros)
constexpr int KSTRIDE = 144;   // LDS bytes per n-row: 64*2 + 16 pad (16B aligned; bank = 4*(n'+g)%32 -> conflict-free b128 reads)

__device__ __forceinline__ unsigned f2bf(float x) {   // f32 -> bf16 bits, RNE
    unsigned u = __builtin_bit_cast(unsigned, x);
    u += 0x7FFFu + ((u >> 16) & 1u);
    return u >> 16;
}

struct ARegs { int4v   q0, q1, q2, q3; };
struct BRegs { float4v r0, r1, r2, r3; };

__global__ __launch_bounds__(256, 2) void mhe_gemm(
        const int* __restrict__ mh, const float* __restrict__ em,
        float* __restrict__ out) {
    __shared__ __align__(16) char lds[2][64 * KSTRIDE];

    const int tid  = threadIdx.x;
    const int lane = tid & 63;
    const int wv   = tid >> 6;
    const int wm   = wv >> 1;        // 16-row strip within block
    const int wn   = wv & 1;         // 32-col half
    const int row0 = (int)blockIdx.x * BM;

    // A addressing: lane holds A[row = row0+wm*16+(lane&15)][k = g8..g8+7] per k-step
    const int g8 = (lane >> 4) << 3;
    const long long arow = row0 + wm * 16 + (lane & 15);
    const int* __restrict__ ap = mh + arow * (long long)K_DIM;

    // B staging: thread covers a 4x4 f32 microtile (k = kg*4+j, n = ng*4+i)
    const int kg = tid >> 4;   // 0..15
    const int ng = tid & 15;   // 0..15

    f32x4 acc0 = {0.f, 0.f, 0.f, 0.f};
    f32x4 acc1 = {0.f, 0.f, 0.f, 0.f};

    char* const lds0 = &lds[0][0];
    char* const lds1 = &lds[1][0];

    auto loadA = [&](ARegs& a, int f0) {
        if (f0 + BK <= K_DIM) {
            const int4v* p0 = (const int4v*)(ap + f0 + g8);
            const int4v* p1 = (const int4v*)(ap + f0 + 32 + g8);
            a.q0 = p0[0]; a.q1 = p0[1];
            a.q2 = p1[0]; a.q3 = p1[1];
        } else {
            a.q0 = {}; a.q1 = {}; a.q2 = {}; a.q3 = {};
            const int b0 = f0 + g8;
            if (b0      < K_DIM) a.q0 = *(const int4v*)(ap + b0);
            if (b0 + 4  < K_DIM) a.q1 = *(const int4v*)(ap + b0 + 4);
            if (b0 + 32 < K_DIM) a.q2 = *(const int4v*)(ap + b0 + 32);
            if (b0 + 36 < K_DIM) a.q3 = *(const int4v*)(ap + b0 + 36);
        }
    };

    auto loadB = [&](BRegs& b, int f0) {
        const int r = f0 + kg * 4;
        if (f0 + BK <= K_DIM) {
            const float* p = em + r * N_DIM + ng * 4;
            b.r0 = *(const float4v*)(p);
            b.r1 = *(const float4v*)(p + N_DIM);
            b.r2 = *(const float4v*)(p + 2 * N_DIM);
            b.r3 = *(const float4v*)(p + 3 * N_DIM);
        } else {
            b.r0 = {}; b.r1 = {}; b.r2 = {}; b.r3 = {};
            if (r + 0 < K_DIM) b.r0 = *(const float4v*)(em + (r + 0) * N_DIM + ng * 4);
            if (r + 1 < K_DIM) b.r1 = *(const float4v*)(em + (r + 1) * N_DIM + ng * 4);
            if (r + 2 < K_DIM) b.r2 = *(const float4v*)(em + (r + 2) * N_DIM + ng * 4);
            if (r + 3 < K_DIM) b.r3 = *(const float4v*)(em + (r + 3) * N_DIM + ng * 4);
        }
    };

    // register 4x4 transpose -> LDS [n][k] bf16
    auto stageB = [&](const BRegs& b, char* buf) {
        char* wp = buf + (ng * 4) * KSTRIDE + kg * 8;
        #pragma unroll
        for (int i = 0; i < 4; ++i) {
            uint2v w = { f2bf(b.r0[i]) | (f2bf(b.r1[i]) << 16),
                         f2bf(b.r2[i]) | (f2bf(b.r3[i]) << 16) };
            *(uint2v*)(wp + i * KSTRIDE) = w;   // ds_write_b64
        }
    };

    // ints 0/1 -> packed bf16 pairs: (a | b<<16) * 0x3F80 == bf16(a) | bf16(b)<<16
    auto packA = [&](int4v qa, int4v qb) -> bf16x8 {
        uint4v w;
        w[0] = (unsigned)(qa[0] | (qa[1] << 16)) * 0x3F80u;
        w[1] = (unsigned)(qa[2] | (qa[3] << 16)) * 0x3F80u;
        w[2] = (unsigned)(qb[0] | (qb[1] << 16)) * 0x3F80u;
        w[3] = (unsigned)(qb[2] | (qb[3] << 16)) * 0x3F80u;
        return __builtin_bit_cast(bf16x8, w);
    };

    const int rboff = (wn * 32 + (lane & 15)) * KSTRIDE + ((lane >> 4) << 4);

    auto compute = [&](const ARegs& a, const char* buf) {
        bf16x8 af0 = packA(a.q0, a.q1);   // k-step 0 (k 0..31)
        bf16x8 af1 = packA(a.q2, a.q3);   // k-step 1 (k 32..63)
        const char* rb = buf + rboff;
        bf16x8 b00 = *(const bf16x8*)(rb);                       // nt=0, ks=0
        bf16x8 b01 = *(const bf16x8*)(rb + 64);                  // nt=0, ks=1
        bf16x8 b10 = *(const bf16x8*)(rb + 16 * KSTRIDE);        // nt=1, ks=0
        bf16x8 b11 = *(const bf16x8*)(rb + 16 * KSTRIDE + 64);   // nt=1, ks=1
        acc0 = __builtin_amdgcn_mfma_f32_16x16x32_bf16(af0, b00, acc0, 0, 0, 0);
        acc1 = __builtin_amdgcn_mfma_f32_16x16x32_bf16(af0, b10, acc1, 0, 0, 0);
        acc0 = __builtin_amdgcn_mfma_f32_16x16x32_bf16(af1, b01, acc0, 0, 0, 0);
        acc1 = __builtin_amdgcn_mfma_f32_16x16x32_bf16(af1, b11, acc1, 0, 0, 0);
    };

    ARegs aC, aN; BRegs bC, bN;
    loadA(aC, 0); loadB(bC, 0);
    stageB(bC, lds0);
    __syncthreads();

    for (int t = 0; t < NCH_PAD; t += 2) {
        loadA(aN, (t + 1) * BK); loadB(bN, (t + 1) * BK);   // prefetch t+1
        compute(aC, lds0);
        stageB(bN, lds1);
        __syncthreads();
        loadA(aC, (t + 2) * BK); loadB(bC, (t + 2) * BK);   // prefetch t+2 (guards zero past K)
        compute(aN, lds1);
        stageB(bC, lds0);
        __syncthreads();
    }

    // C/D layout: col = lane&15, row = (lane>>4)*4 + i   [m89-verified]
    const int crow = row0 + wm * 16 + ((lane >> 4) << 2);
    const int ccol = wn * 32 + (lane & 15);
    #pragma unroll
    for (int i = 0; i < 4; ++i) {
        out[(crow + i) * N_DIM + ccol]      = acc0[i];
        out[(crow + i) * N_DIM + ccol + 16] = acc1[i];
    }
}

extern "C" void kernel_launch(void* const* d_in, const int* in_sizes, int n_in,
                              void* d_out, int out_size, void* d_ws, size_t ws_size,
                              hipStream_t stream) {
    const int*   mh  = (const int*)d_in[0];
    const float* em  = (const float*)d_in[1];
    float*       out = (float*)d_out;
    (void)in_sizes; (void)n_in; (void)out_size; (void)d_ws; (void)ws_size;

    dim3 grid(M_DIM / BM);   // 512 blocks (~2 per CU)
    dim3 block(256);         // 4 waves
    mhe_gemm<<<grid, block, 0, stream>>>(mh, em, out);
}